// Round 1
// baseline (3494.905 us; speedup 1.0000x reference)
//
#include <hip/hip_runtime.h>

#define NUM_ENT 10000
#define NUM_REL 50
#define HID 64
#define NTRIP 500000

// ---------------- bucketing by relation ----------------

__global__ void k_hist(const int* __restrict__ r, int* __restrict__ hist) {
    __shared__ int lh[NUM_REL];
    int tid = threadIdx.x;
    if (tid < NUM_REL) lh[tid] = 0;
    __syncthreads();
    int i = blockIdx.x * blockDim.x + tid;
    if (i < NTRIP) atomicAdd(&lh[r[i]], 1);
    __syncthreads();
    if (tid < NUM_REL && lh[tid] > 0) atomicAdd(&hist[tid], lh[tid]);
}

__global__ void k_scan(const int* __restrict__ hist, int* __restrict__ off,
                       int* __restrict__ cur) {
    if (threadIdx.x == 0 && blockIdx.x == 0) {
        int s = 0;
        for (int i = 0; i < NUM_REL; i++) { off[i] = s; cur[i] = s; s += hist[i]; }
        off[NUM_REL] = s;
    }
}

__global__ void k_bucket(const int* __restrict__ h, const int* __restrict__ r,
                         const int* __restrict__ t, int* __restrict__ cur,
                         int2* __restrict__ bucket) {
    __shared__ int lcnt[NUM_REL];
    __shared__ int lbase[NUM_REL];
    int tid = threadIdx.x;
    if (tid < NUM_REL) lcnt[tid] = 0;
    __syncthreads();
    int i = blockIdx.x * blockDim.x + tid;
    int rr = -1, lpos = 0;
    if (i < NTRIP) { rr = r[i]; lpos = atomicAdd(&lcnt[rr], 1); }
    __syncthreads();
    if (tid < NUM_REL && lcnt[tid] > 0) lbase[tid] = atomicAdd(&cur[tid], lcnt[tid]);
    __syncthreads();
    if (i < NTRIP) bucket[lbase[rr] + lpos] = make_int2(h[i], t[i]);
}

// ---------------- layer 0 ----------------

// U0[e,d] = Wres0[d,e]  (transpose 64x10000 -> 10000x64, LDS-tiled)
__global__ void k_init_u0(const float* __restrict__ Wres0, float* __restrict__ U0) {
    __shared__ float tile[64][65];
    int e0 = blockIdx.x * 64;
    for (int i = threadIdx.x; i < 64 * 64; i += 256) {
        int dd = i >> 6, xx = i & 63;
        if (e0 + xx < NUM_ENT) tile[xx][dd] = Wres0[dd * NUM_ENT + e0 + xx];
    }
    __syncthreads();
    for (int i = threadIdx.x; i < 64 * 64; i += 256) {
        int ee = i >> 6, dd = i & 63;
        if (e0 + ee < NUM_ENT) U0[(e0 + ee) * HID + dd] = tile[ee][dd];
    }
}

// one block per (relation r, output dim d): stream row Wme0[r*64+d,:] into LDS
// then scatter-add row[h]+Wmr0diag into U0[t*64+d] for all triplets of r.
__global__ void k_l0(const float* __restrict__ Wme0, const float* __restrict__ Wmr0,
                     const int* __restrict__ off, const int2* __restrict__ bucket,
                     float* __restrict__ U0) {
    __shared__ float row[NUM_ENT];
    int rr = blockIdx.x >> 6;
    int d  = blockIdx.x & 63;
    const float4* src4 = (const float4*)(Wme0 + (size_t)(rr * HID + d) * NUM_ENT);
    float4* row4 = (float4*)row;
    for (int i = threadIdx.x; i < NUM_ENT / 4; i += blockDim.x) row4[i] = src4[i];
    __syncthreads();
    float wd0 = Wmr0[(size_t)(rr * HID + d) * NUM_REL + rr];
    int b0 = off[rr], b1 = off[rr + 1];
    for (int i = b0 + threadIdx.x; i < b1; i += blockDim.x) {
        int2 ht = bucket[i];
        atomicAdd(&U0[(size_t)ht.y * HID + d], row[ht.x] + wd0);
    }
}

__global__ void k_lrelu(float* __restrict__ x, int n) {
    int i = blockIdx.x * blockDim.x + threadIdx.x;
    if (i < n) { float v = x[i]; x[i] = v >= 0.0f ? v : 0.01f * v; }
}

// ---------------- layer 1 ----------------

// diag1[r,d] = sum_k Wpr0[k,r]*Wmr1[(r*64+d),k]; out_rel[r,d] = sum_k Wpr0[k,r]*Wpr1[d,k]
__global__ void k_rel(const float* __restrict__ Wpr0, const float* __restrict__ Wmr1,
                      const float* __restrict__ Wpr1, float* __restrict__ diag1,
                      float* __restrict__ outrel) {
    __shared__ float wp[HID];
    int rr = blockIdx.x, d = threadIdx.x;
    wp[d] = Wpr0[d * NUM_REL + rr];
    __syncthreads();
    float s1 = 0.0f, s2 = 0.0f;
    const float* wmr = Wmr1 + (size_t)(rr * HID + d) * HID;
    const float* wpr = Wpr1 + d * HID;
    for (int k = 0; k < HID; k++) { s1 += wp[k] * wmr[k]; s2 += wp[k] * wpr[k]; }
    diag1[rr * HID + d] = s1;
    outrel[rr * HID + d] = s2;
}

// out[e,d] = sum_k A[e,k] * Wres1[d,k]
__global__ void k_init_u1(const float* __restrict__ A, const float* __restrict__ Wres1,
                          float* __restrict__ out) {
    __shared__ float W[HID][HID + 1];
    int tid = threadIdx.x;
    for (int i = tid; i < HID * HID; i += 256) W[i >> 6][i & 63] = Wres1[i];
    __syncthreads();
    int g = blockIdx.x * 256 + tid;
    int e = g >> 6, d = g & 63;
    if (e >= NUM_ENT) return;
    const float4* arow = (const float4*)(A + (size_t)e * HID);
    float acc = 0.0f;
#pragma unroll
    for (int k4 = 0; k4 < 16; k4++) {
        float4 a = arow[k4];
        acc = fmaf(a.x, W[d][k4 * 4 + 0], acc);
        acc = fmaf(a.y, W[d][k4 * 4 + 1], acc);
        acc = fmaf(a.z, W[d][k4 * 4 + 2], acc);
        acc = fmaf(a.w, W[d][k4 * 4 + 3], acc);
    }
    out[g] = acc;
}

#define L1_CHUNKS 16

// per-triplet matvec: msg = A[h,:] @ Wme1_r^T + diag1[r,:], atomic-add into out[t,:]
// lane = triplet; Wme1/diag1 accesses are wave-uniform -> scalar loads co-issued.
__global__ void k_l1(const float* __restrict__ A, const float* __restrict__ Wme1,
                     const int* __restrict__ off, const int2* __restrict__ bucket,
                     const float* __restrict__ diag1, float* __restrict__ out) {
    int rr = blockIdx.x / L1_CHUNKS;
    int chunk = blockIdx.x % L1_CHUNKS;
    int b0 = off[rr], b1 = off[rr + 1];
    for (int i = b0 + chunk * 256 + (int)threadIdx.x; i < b1; i += L1_CHUNKS * 256) {
        int2 ht = bucket[i];
        const float4* arow = (const float4*)(A + (size_t)ht.x * HID);
        float4 a[16];
#pragma unroll
        for (int j = 0; j < 16; j++) a[j] = arow[j];
        float* op = out + (size_t)ht.y * HID;
#pragma unroll 4
        for (int d = 0; d < HID; d++) {
            const float4* m4 = (const float4*)(Wme1 + (size_t)(rr * HID + d) * HID);
            float acc = diag1[rr * HID + d];
#pragma unroll
            for (int k = 0; k < 16; k++) {
                float4 m = m4[k];
                acc = fmaf(a[k].x, m.x, acc);
                acc = fmaf(a[k].y, m.y, acc);
                acc = fmaf(a[k].z, m.z, acc);
                acc = fmaf(a[k].w, m.w, acc);
            }
            atomicAdd(op + d, acc);
        }
    }
}

// ---------------- launch ----------------

extern "C" void kernel_launch(void* const* d_in, const int* in_sizes, int n_in,
                              void* d_out, int out_size, void* d_ws, size_t ws_size,
                              hipStream_t stream) {
    const float* Wres0 = (const float*)d_in[0];
    const float* Wme0  = (const float*)d_in[1];
    const float* Wmr0  = (const float*)d_in[2];
    const float* Wpr0  = (const float*)d_in[3];
    const float* Wres1 = (const float*)d_in[4];
    const float* Wme1  = (const float*)d_in[5];
    const float* Wmr1  = (const float*)d_in[6];
    const float* Wpr1  = (const float*)d_in[7];
    const int* h = (const int*)d_in[8];
    const int* r = (const int*)d_in[9];
    const int* t = (const int*)d_in[10];
    float* out = (float*)d_out;  // [640000 ent | 3200 rel]

    char* ws = (char*)d_ws;
    int2*  bucket = (int2*)ws;                    // 4,000,000 B
    float* U0     = (float*)(ws + 4000000);       // 2,560,000 B (U0, then A in-place)
    float* diag1  = (float*)(ws + 6560000);       // 12,800 B
    int*   hist   = (int*)(ws + 6572800);
    int*   off    = (int*)(ws + 6573056);
    int*   cur    = (int*)(ws + 6573312);

    hipMemsetAsync(hist, 0, NUM_REL * sizeof(int), stream);

    int nb = (NTRIP + 255) / 256;
    k_hist<<<nb, 256, 0, stream>>>(r, hist);
    k_scan<<<1, 64, 0, stream>>>(hist, off, cur);
    k_bucket<<<nb, 256, 0, stream>>>(h, r, t, cur, bucket);

    k_init_u0<<<(NUM_ENT + 63) / 64, 256, 0, stream>>>(Wres0, U0);
    k_l0<<<NUM_REL * HID, 256, 0, stream>>>(Wme0, Wmr0, off, bucket, U0);
    k_lrelu<<<(NUM_ENT * HID + 255) / 256, 256, 0, stream>>>(U0, NUM_ENT * HID);  // U0 -> A

    k_rel<<<NUM_REL, HID, 0, stream>>>(Wpr0, Wmr1, Wpr1, diag1, out + NUM_ENT * HID);
    k_init_u1<<<(NUM_ENT * HID) / 256, 256, 0, stream>>>(U0, Wres1, out);
    k_l1<<<NUM_REL * L1_CHUNKS, 256, 0, stream>>>(U0, Wme1, off, bucket, diag1, out);
    k_lrelu<<<(NUM_ENT * HID + 255) / 256, 256, 0, stream>>>(out, NUM_ENT * HID);
}

// Round 2
// 343.276 us; speedup vs baseline: 10.1810x; 10.1810x over previous
//
#include <hip/hip_runtime.h>

#define NUM_ENT 10000
#define NUM_REL 50
#define HID 64
#define NTRIP 500000

// ============================================================
// fast path: t-sorted, atomic-free scatter
// ============================================================

// bins[(r/G)*10000 + t]++
__global__ __launch_bounds__(256) void k_thist(const int* __restrict__ r,
                                               const int* __restrict__ t,
                                               int* __restrict__ bins, int G) {
    int i = blockIdx.x * 256 + threadIdx.x;
    if (i < NTRIP) atomicAdd(&bins[(r[i] / G) * NUM_ENT + t[i]], 1);
}

// single-block exclusive scan over nbins; writes toff[i]=excl, bins[i]=excl (cursor),
// toff[nbins]=total.
__global__ __launch_bounds__(256) void k_scan(int* __restrict__ bins,
                                              int* __restrict__ toff, int nbins) {
    __shared__ int wsum[4];
    int tid = threadIdx.x, lane = tid & 63, w = tid >> 6;
    int running = 0;
    for (int base = 0; base < nbins; base += 256) {
        int i = base + tid;
        int s = (i < nbins) ? bins[i] : 0;
        int v = s;
        for (int off = 1; off < 64; off <<= 1) {
            int u = __shfl_up(v, off);
            if (lane >= off) v += u;
        }
        if (lane == 63) wsum[w] = v;
        __syncthreads();
        int t0 = wsum[0], t1 = wsum[1], t2 = wsum[2], t3 = wsum[3];
        int woff = (w > 0 ? t0 : 0) + (w > 1 ? t1 : 0) + (w > 2 ? t2 : 0);
        int excl = running + woff + (v - s);
        if (i < nbins) { toff[i] = excl; bins[i] = excl; }
        running += t0 + t1 + t2 + t3;
        __syncthreads();
    }
    if (tid == 0) toff[nbins] = running;
}

// scatter (h | r<<14) into bucket2 at t-sorted positions
__global__ __launch_bounds__(256) void k_tscatter(const int* __restrict__ h,
                                                  const int* __restrict__ r,
                                                  const int* __restrict__ t,
                                                  int* __restrict__ cur,
                                                  unsigned* __restrict__ bucket2, int G) {
    int i = blockIdx.x * 256 + threadIdx.x;
    if (i < NTRIP) {
        int rr = r[i];
        int pos = atomicAdd(&cur[(rr / G) * NUM_ENT + t[i]], 1);
        bucket2[pos] = (unsigned)h[i] | ((unsigned)rr << 14);
    }
}

// diag0[r*64+d] = Wmr0[(r*64+d)*50 + r]
__global__ void k_diag0(const float* __restrict__ Wmr0, float* __restrict__ diag0) {
    int i = blockIdx.x * 256 + threadIdx.x;
    if (i < NUM_REL * HID) diag0[i] = Wmr0[(size_t)i * NUM_REL + (i >> 6)];
}

// U0[e,d] = Wres0[d,e]
__global__ void k_init_u0(const float* __restrict__ Wres0, float* __restrict__ U0) {
    __shared__ float tile[64][65];
    int e0 = blockIdx.x * 64;
    for (int i = threadIdx.x; i < 64 * 64; i += 256) {
        int dd = i >> 6, xx = i & 63;
        if (e0 + xx < NUM_ENT) tile[xx][dd] = Wres0[dd * NUM_ENT + e0 + xx];
    }
    __syncthreads();
    for (int i = threadIdx.x; i < 64 * 64; i += 256) {
        int ee = i >> 6, dd = i & 63;
        if (e0 + ee < NUM_ENT) U0[(e0 + ee) * HID + dd] = tile[ee][dd];
    }
}

// P[e*RS + (rr-r0)*64 + d] = Wme0[(rr*64+d)*NUM_ENT + e], per (rr, e-tile)
__global__ __launch_bounds__(256) void k_transpose(const float* __restrict__ W,
                                                   float* __restrict__ P,
                                                   int r0, int RS) {
    __shared__ float tile[64][65];
    int rr = r0 + blockIdx.y;
    int e0 = blockIdx.x * 64;
    int tid = threadIdx.x;
    for (int i = tid; i < 4096; i += 256) {
        int dd = i >> 6, xx = i & 63;
        int e = e0 + xx;
        tile[dd][xx] = (e < NUM_ENT) ? W[(size_t)(rr * HID + dd) * NUM_ENT + e] : 0.f;
    }
    __syncthreads();
    for (int i = tid; i < 4096; i += 256) {
        int ee = i >> 6, dd = i & 63;
        int e = e0 + ee;
        if (e < NUM_ENT) P[(size_t)e * RS + (size_t)blockIdx.y * 64 + dd] = tile[dd][ee];
    }
}

// B[e*RS + (rr-r0)*64 + d] = sum_k A[e,k] * Wme1[(rr*64+d)*64 + k]
#define GB_PAD 68
__global__ __launch_bounds__(256) void k_gemmB(const float* __restrict__ A,
                                               const float* __restrict__ Wme1,
                                               float* __restrict__ B, int r0, int RS) {
    __shared__ __align__(16) float Al[64][GB_PAD];  // [k][e]
    __shared__ __align__(16) float Wl[64][GB_PAD];  // [k][d]
    int rr = r0 + blockIdx.y;
    int e0 = blockIdx.x * 64;
    int tid = threadIdx.x;
    for (int i = tid; i < 4096; i += 256) {
        int ee = i >> 6, kk = i & 63;
        int e = e0 + ee;
        Al[kk][ee] = (e < NUM_ENT) ? A[(size_t)e * HID + kk] : 0.f;
    }
    for (int i = tid; i < 4096; i += 256) {
        int dd = i >> 6, kk = i & 63;
        Wl[kk][dd] = Wme1[(size_t)(rr * HID + dd) * HID + kk];
    }
    __syncthreads();
    int di = tid & 15, ei = tid >> 4;
    float acc[4][4] = {};
#pragma unroll 4
    for (int k = 0; k < 64; ++k) {
        float4 a = *(const float4*)&Al[k][ei * 4];
        float4 w = *(const float4*)&Wl[k][di * 4];
        acc[0][0] = fmaf(a.x, w.x, acc[0][0]); acc[0][1] = fmaf(a.x, w.y, acc[0][1]);
        acc[0][2] = fmaf(a.x, w.z, acc[0][2]); acc[0][3] = fmaf(a.x, w.w, acc[0][3]);
        acc[1][0] = fmaf(a.y, w.x, acc[1][0]); acc[1][1] = fmaf(a.y, w.y, acc[1][1]);
        acc[1][2] = fmaf(a.y, w.z, acc[1][2]); acc[1][3] = fmaf(a.y, w.w, acc[1][3]);
        acc[2][0] = fmaf(a.z, w.x, acc[2][0]); acc[2][1] = fmaf(a.z, w.y, acc[2][1]);
        acc[2][2] = fmaf(a.z, w.z, acc[2][2]); acc[2][3] = fmaf(a.z, w.w, acc[2][3]);
        acc[3][0] = fmaf(a.w, w.x, acc[3][0]); acc[3][1] = fmaf(a.w, w.y, acc[3][1]);
        acc[3][2] = fmaf(a.w, w.z, acc[3][2]); acc[3][3] = fmaf(a.w, w.w, acc[3][3]);
    }
#pragma unroll
    for (int j = 0; j < 4; ++j) {
        int e = e0 + ei * 4 + j;
        if (e < NUM_ENT) {
            float4 v = make_float4(acc[j][0], acc[j][1], acc[j][2], acc[j][3]);
            *(float4*)&B[(size_t)e * RS + (size_t)blockIdx.y * 64 + di * 4] = v;
        }
    }
}

// wave per tail: target[e,:] += sum_j (table[h_j, rr_j-g0, :] + diag[rr_j,:]); optional lrelu
__global__ __launch_bounds__(256) void k_scatter(const float* __restrict__ table,
                                                 const float* __restrict__ diag,
                                                 const int* __restrict__ toff,
                                                 const unsigned* __restrict__ bucket2,
                                                 float* __restrict__ target,
                                                 int RS, int g0, int applyAct) {
    int e = __builtin_amdgcn_readfirstlane(blockIdx.x * 4 + (threadIdx.x >> 6));
    int d = threadIdx.x & 63;
    int j0 = toff[e], j1 = toff[e + 1];
    float acc = 0.f, acc2 = 0.f;
    int j = j0;
    for (; j + 2 <= j1; j += 2) {
        unsigned hr0 = bucket2[j], hr1 = bucket2[j + 1];
        int h0 = hr0 & 16383, r0 = hr0 >> 14;
        int h1 = hr1 & 16383, r1 = hr1 >> 14;
        float v0 = table[(size_t)h0 * RS + (size_t)(r0 - g0) * 64 + d];
        float v1 = table[(size_t)h1 * RS + (size_t)(r1 - g0) * 64 + d];
        acc  += v0 + diag[r0 * 64 + d];
        acc2 += v1 + diag[r1 * 64 + d];
    }
    if (j < j1) {
        unsigned hr0 = bucket2[j];
        int h0 = hr0 & 16383, r0 = hr0 >> 14;
        acc += table[(size_t)h0 * RS + (size_t)(r0 - g0) * 64 + d] + diag[r0 * 64 + d];
    }
    acc += acc2;
    float v = target[e * HID + d] + acc;
    if (applyAct) v = (v >= 0.f) ? v : 0.01f * v;
    target[e * HID + d] = v;
}

// diag1[r,d] = sum_k Wpr0[k,r]*Wmr1[(r*64+d),k]; outrel[r,d] = sum_k Wpr0[k,r]*Wpr1[d,k]
__global__ void k_rel(const float* __restrict__ Wpr0, const float* __restrict__ Wmr1,
                      const float* __restrict__ Wpr1, float* __restrict__ diag1,
                      float* __restrict__ outrel) {
    __shared__ float wp[HID];
    int rr = blockIdx.x, d = threadIdx.x;
    wp[d] = Wpr0[d * NUM_REL + rr];
    __syncthreads();
    float s1 = 0.0f, s2 = 0.0f;
    const float* wmr = Wmr1 + (size_t)(rr * HID + d) * HID;
    const float* wpr = Wpr1 + d * HID;
    for (int k = 0; k < HID; k++) { s1 += wp[k] * wmr[k]; s2 += wp[k] * wpr[k]; }
    diag1[rr * HID + d] = s1;
    outrel[rr * HID + d] = s2;
}

// out[e,d] = sum_k A[e,k] * Wres1[d,k]
__global__ void k_init_u1(const float* __restrict__ A, const float* __restrict__ Wres1,
                          float* __restrict__ out) {
    __shared__ float W[HID][HID + 1];
    int tid = threadIdx.x;
    for (int i = tid; i < HID * HID; i += 256) W[i >> 6][i & 63] = Wres1[i];
    __syncthreads();
    int g = blockIdx.x * 256 + tid;
    int e = g >> 6, d = g & 63;
    if (e >= NUM_ENT) return;
    const float4* arow = (const float4*)(A + (size_t)e * HID);
    float acc = 0.0f;
#pragma unroll
    for (int k4 = 0; k4 < 16; k4++) {
        float4 a = arow[k4];
        acc = fmaf(a.x, W[d][k4 * 4 + 0], acc);
        acc = fmaf(a.y, W[d][k4 * 4 + 1], acc);
        acc = fmaf(a.z, W[d][k4 * 4 + 2], acc);
        acc = fmaf(a.w, W[d][k4 * 4 + 3], acc);
    }
    out[g] = acc;
}

// ============================================================
// fallback path (round-1 atomic kernels) — used only if ws too small
// ============================================================

__global__ void k_hist(const int* __restrict__ r, int* __restrict__ hist) {
    __shared__ int lh[NUM_REL];
    int tid = threadIdx.x;
    if (tid < NUM_REL) lh[tid] = 0;
    __syncthreads();
    int i = blockIdx.x * blockDim.x + tid;
    if (i < NTRIP) atomicAdd(&lh[r[i]], 1);
    __syncthreads();
    if (tid < NUM_REL && lh[tid] > 0) atomicAdd(&hist[tid], lh[tid]);
}

__global__ void k_scan_small(const int* __restrict__ hist, int* __restrict__ off,
                             int* __restrict__ cur) {
    if (threadIdx.x == 0 && blockIdx.x == 0) {
        int s = 0;
        for (int i = 0; i < NUM_REL; i++) { off[i] = s; cur[i] = s; s += hist[i]; }
        off[NUM_REL] = s;
    }
}

__global__ void k_bucket(const int* __restrict__ h, const int* __restrict__ r,
                         const int* __restrict__ t, int* __restrict__ cur,
                         int2* __restrict__ bucket) {
    __shared__ int lcnt[NUM_REL];
    __shared__ int lbase[NUM_REL];
    int tid = threadIdx.x;
    if (tid < NUM_REL) lcnt[tid] = 0;
    __syncthreads();
    int i = blockIdx.x * blockDim.x + tid;
    int rr = -1, lpos = 0;
    if (i < NTRIP) { rr = r[i]; lpos = atomicAdd(&lcnt[rr], 1); }
    __syncthreads();
    if (tid < NUM_REL && lcnt[tid] > 0) lbase[tid] = atomicAdd(&cur[tid], lcnt[tid]);
    __syncthreads();
    if (i < NTRIP) bucket[lbase[rr] + lpos] = make_int2(h[i], t[i]);
}

__global__ void k_l0(const float* __restrict__ Wme0, const float* __restrict__ Wmr0,
                     const int* __restrict__ off, const int2* __restrict__ bucket,
                     float* __restrict__ U0) {
    __shared__ float row[NUM_ENT];
    int rr = blockIdx.x >> 6;
    int d  = blockIdx.x & 63;
    const float4* src4 = (const float4*)(Wme0 + (size_t)(rr * HID + d) * NUM_ENT);
    float4* row4 = (float4*)row;
    for (int i = threadIdx.x; i < NUM_ENT / 4; i += blockDim.x) row4[i] = src4[i];
    __syncthreads();
    float wd0 = Wmr0[(size_t)(rr * HID + d) * NUM_REL + rr];
    int b0 = off[rr], b1 = off[rr + 1];
    for (int i = b0 + threadIdx.x; i < b1; i += blockDim.x) {
        int2 ht = bucket[i];
        atomicAdd(&U0[(size_t)ht.y * HID + d], row[ht.x] + wd0);
    }
}

__global__ void k_lrelu(float* __restrict__ x, int n) {
    int i = blockIdx.x * blockDim.x + threadIdx.x;
    if (i < n) { float v = x[i]; x[i] = v >= 0.0f ? v : 0.01f * v; }
}

#define L1_CHUNKS 16
__global__ void k_l1(const float* __restrict__ A, const float* __restrict__ Wme1,
                     const int* __restrict__ off, const int2* __restrict__ bucket,
                     const float* __restrict__ diag1, float* __restrict__ out) {
    int rr = blockIdx.x / L1_CHUNKS;
    int chunk = blockIdx.x % L1_CHUNKS;
    int b0 = off[rr], b1 = off[rr + 1];
    for (int i = b0 + chunk * 256 + (int)threadIdx.x; i < b1; i += L1_CHUNKS * 256) {
        int2 ht = bucket[i];
        const float4* arow = (const float4*)(A + (size_t)ht.x * HID);
        float4 a[16];
#pragma unroll
        for (int j = 0; j < 16; j++) a[j] = arow[j];
        float* op = out + (size_t)ht.y * HID;
#pragma unroll 4
        for (int d = 0; d < HID; d++) {
            const float4* m4 = (const float4*)(Wme1 + (size_t)(rr * HID + d) * HID);
            float acc = diag1[rr * HID + d];
#pragma unroll
            for (int k = 0; k < 16; k++) {
                float4 m = m4[k];
                acc = fmaf(a[k].x, m.x, acc);
                acc = fmaf(a[k].y, m.y, acc);
                acc = fmaf(a[k].z, m.z, acc);
                acc = fmaf(a[k].w, m.w, acc);
            }
            atomicAdd(op + d, acc);
        }
    }
}

// ============================================================
// launch
// ============================================================

static inline size_t align_up(size_t x, size_t a) { return (x + a - 1) & ~(a - 1); }

extern "C" void kernel_launch(void* const* d_in, const int* in_sizes, int n_in,
                              void* d_out, int out_size, void* d_ws, size_t ws_size,
                              hipStream_t stream) {
    const float* Wres0 = (const float*)d_in[0];
    const float* Wme0  = (const float*)d_in[1];
    const float* Wmr0  = (const float*)d_in[2];
    const float* Wpr0  = (const float*)d_in[3];
    const float* Wres1 = (const float*)d_in[4];
    const float* Wme1  = (const float*)d_in[5];
    const float* Wmr1  = (const float*)d_in[6];
    const float* Wpr1  = (const float*)d_in[7];
    const int* h = (const int*)d_in[8];
    const int* r = (const int*)d_in[9];
    const int* t = (const int*)d_in[10];
    float* out = (float*)d_out;  // [640000 ent | 3200 rel]

    char* ws = (char*)d_ws;
    const int nbt = (NTRIP + 255) / 256;       // 1954
    const int net = (NUM_ENT + 63) / 64;       // 157

    // pick largest relation-group size G that fits in ws
    int G = 0, ngroups = 0;
    size_t oP = 0, oB2 = 0, oToff = 0, oBins = 0, oU0 = 0, oD0 = 0, oD1 = 0;
    for (int g = NUM_REL; g >= 1; --g) {
        int ng = (NUM_REL + g - 1) / g;
        size_t p = 0;
        size_t P_   = p; p += align_up((size_t)g * 64 * NUM_ENT * 4, 256);
        size_t B2_  = p; p += align_up((size_t)NTRIP * 4, 256);
        size_t Tf_  = p; p += align_up(((size_t)ng * NUM_ENT + 1) * 4, 256);
        size_t Bn_  = p; p += align_up((size_t)ng * NUM_ENT * 4, 256);
        size_t U0_  = p; p += align_up((size_t)NUM_ENT * HID * 4, 256);
        size_t D0_  = p; p += align_up((size_t)NUM_REL * HID * 4, 256);
        size_t D1_  = p; p += align_up((size_t)NUM_REL * HID * 4, 256);
        if (p <= ws_size) {
            G = g; ngroups = ng;
            oP = P_; oB2 = B2_; oToff = Tf_; oBins = Bn_; oU0 = U0_; oD0 = D0_; oD1 = D1_;
            break;
        }
    }

    if (G >= 1) {
        float*    P       = (float*)(ws + oP);
        unsigned* bucket2 = (unsigned*)(ws + oB2);
        int*      toff    = (int*)(ws + oToff);
        int*      bins    = (int*)(ws + oBins);
        float*    U0      = (float*)(ws + oU0);
        float*    diag0   = (float*)(ws + oD0);
        float*    diag1   = (float*)(ws + oD1);
        int nbins = ngroups * NUM_ENT;
        int RS = G * 64;

        hipMemsetAsync(bins, 0, (size_t)nbins * 4, stream);
        k_thist<<<nbt, 256, 0, stream>>>(r, t, bins, G);
        k_scan<<<1, 256, 0, stream>>>(bins, toff, nbins);
        k_tscatter<<<nbt, 256, 0, stream>>>(h, r, t, bins, bucket2, G);

        k_diag0<<<(NUM_REL * HID + 255) / 256, 256, 0, stream>>>(Wmr0, diag0);
        k_init_u0<<<net, 256, 0, stream>>>(Wres0, U0);

        // layer 0: per group, transpose Wme0 chunk then tail-owned scatter
        for (int g = 0; g < ngroups; ++g) {
            int grels = (g == ngroups - 1) ? (NUM_REL - g * G) : G;
            k_transpose<<<dim3(net, grels), 256, 0, stream>>>(Wme0, P, g * G, RS);
            k_scatter<<<(NUM_ENT + 3) / 4, 256, 0, stream>>>(
                P, diag0, toff + (size_t)g * NUM_ENT, bucket2, U0, RS, g * G,
                (g == ngroups - 1) ? 1 : 0);
        }
        // U0 is now A (activated)

        k_rel<<<NUM_REL, HID, 0, stream>>>(Wpr0, Wmr1, Wpr1, diag1, out + NUM_ENT * HID);
        k_init_u1<<<(NUM_ENT * HID) / 256, 256, 0, stream>>>(U0, Wres1, out);

        // layer 1: per group, dense B = A @ Wme1_r^T then tail-owned scatter
        for (int g = 0; g < ngroups; ++g) {
            int grels = (g == ngroups - 1) ? (NUM_REL - g * G) : G;
            k_gemmB<<<dim3(net, grels), 256, 0, stream>>>(U0, Wme1, P, g * G, RS);
            k_scatter<<<(NUM_ENT + 3) / 4, 256, 0, stream>>>(
                P, diag1, toff + (size_t)g * NUM_ENT, bucket2, out, RS, g * G,
                (g == ngroups - 1) ? 1 : 0);
        }
        return;
    }

    // ---------- fallback: round-1 atomic path (ws >= 6.6 MB known-good) ----------
    {
        int2*  bucket = (int2*)ws;                    // 4,000,000 B
        float* U0     = (float*)(ws + 4000000);       // 2,560,000 B
        float* diag1  = (float*)(ws + 6560000);       // 12,800 B
        int*   hist   = (int*)(ws + 6572800);
        int*   off    = (int*)(ws + 6573056);
        int*   cur    = (int*)(ws + 6573312);

        hipMemsetAsync(hist, 0, NUM_REL * sizeof(int), stream);
        k_hist<<<nbt, 256, 0, stream>>>(r, hist);
        k_scan_small<<<1, 64, 0, stream>>>(hist, off, cur);
        k_bucket<<<nbt, 256, 0, stream>>>(h, r, t, cur, bucket);

        k_init_u0<<<net, 256, 0, stream>>>(Wres0, U0);
        k_l0<<<NUM_REL * HID, 256, 0, stream>>>(Wme0, Wmr0, off, bucket, U0);
        k_lrelu<<<(NUM_ENT * HID + 255) / 256, 256, 0, stream>>>(U0, NUM_ENT * HID);

        k_rel<<<NUM_REL, HID, 0, stream>>>(Wpr0, Wmr1, Wpr1, diag1, out + NUM_ENT * HID);
        k_init_u1<<<(NUM_ENT * HID) / 256, 256, 0, stream>>>(U0, Wres1, out);
        k_l1<<<NUM_REL * L1_CHUNKS, 256, 0, stream>>>(U0, Wme1, off, bucket, diag1, out);
        k_lrelu<<<(NUM_ENT * HID + 255) / 256, 256, 0, stream>>>(out, NUM_ENT * HID);
    }
}

// Round 3
// 285.516 us; speedup vs baseline: 12.2407x; 1.2023x over previous
//
#include <hip/hip_runtime.h>

#define NUM_ENT 10000
#define NUM_REL 50
#define HID 64
#define NTRIP 500000

// bf16 helpers (RNE, no NaN handling needed for this data)
static __device__ __forceinline__ unsigned short f2bf(float x) {
    unsigned u = __float_as_uint(x);
    return (unsigned short)((u + 0x7FFFu + ((u >> 16) & 1u)) >> 16);
}
static __device__ __forceinline__ float bf2f(unsigned short b) {
    return __uint_as_float((unsigned)b << 16);
}

// ============================================================
// fast path: t-sorted, atomic-free scatter; bf16 message tables
// ============================================================

__global__ __launch_bounds__(256) void k_thist(const int* __restrict__ r,
                                               const int* __restrict__ t,
                                               int* __restrict__ bins, int G) {
    int i = blockIdx.x * 256 + threadIdx.x;
    if (i < NTRIP) atomicAdd(&bins[(r[i] / G) * NUM_ENT + t[i]], 1);
}

// single-block 1024-thread exclusive scan; toff[i]=excl, bins[i]=excl (cursor)
__global__ __launch_bounds__(1024) void k_scan(int* __restrict__ bins,
                                               int* __restrict__ toff, int nbins) {
    __shared__ int wsum[16];
    int tid = threadIdx.x, lane = tid & 63, w = tid >> 6;
    int running = 0;
    for (int base = 0; base < nbins; base += 1024) {
        int i = base + tid;
        int s = (i < nbins) ? bins[i] : 0;
        int v = s;
        for (int off = 1; off < 64; off <<= 1) {
            int u = __shfl_up(v, off);
            if (lane >= off) v += u;
        }
        if (lane == 63) wsum[w] = v;
        __syncthreads();
        int woff = 0, tot = 0;
#pragma unroll
        for (int k = 0; k < 16; ++k) {
            int ws = wsum[k];
            woff += (k < w) ? ws : 0;
            tot += ws;
        }
        int excl = running + woff + (v - s);
        if (i < nbins) { toff[i] = excl; bins[i] = excl; }
        running += tot;
        __syncthreads();
    }
    if (tid == 0) toff[nbins] = running;
}

__global__ __launch_bounds__(256) void k_tscatter(const int* __restrict__ h,
                                                  const int* __restrict__ r,
                                                  const int* __restrict__ t,
                                                  int* __restrict__ cur,
                                                  unsigned* __restrict__ bucket2, int G) {
    int i = blockIdx.x * 256 + threadIdx.x;
    if (i < NTRIP) {
        int rr = r[i];
        int pos = atomicAdd(&cur[(rr / G) * NUM_ENT + t[i]], 1);
        bucket2[pos] = (unsigned)h[i] | ((unsigned)rr << 14);
    }
}

// diag0[r*64+d] = Wmr0[(r*64+d)*50 + r]
__global__ void k_diag0(const float* __restrict__ Wmr0, float* __restrict__ diag0) {
    int i = blockIdx.x * 256 + threadIdx.x;
    if (i < NUM_REL * HID) diag0[i] = Wmr0[(size_t)i * NUM_REL + (i >> 6)];
}

// U0[e,d] = Wres0[d,e]
__global__ void k_init_u0(const float* __restrict__ Wres0, float* __restrict__ U0) {
    __shared__ float tile[64][65];
    int e0 = blockIdx.x * 64;
    for (int i = threadIdx.x; i < 64 * 64; i += 256) {
        int dd = i >> 6, xx = i & 63;
        if (e0 + xx < NUM_ENT) tile[xx][dd] = Wres0[dd * NUM_ENT + e0 + xx];
    }
    __syncthreads();
    for (int i = threadIdx.x; i < 64 * 64; i += 256) {
        int ee = i >> 6, dd = i & 63;
        if (e0 + ee < NUM_ENT) U0[(e0 + ee) * HID + dd] = tile[ee][dd];
    }
}

// WT1[r*4096 + k*64 + d] = Wme1[(r*64+d)*64 + k]   (one block per r)
__global__ __launch_bounds__(256) void k_transposeW1(const float* __restrict__ W,
                                                     float* __restrict__ WT) {
    __shared__ float tl[64][65];
    int rr = blockIdx.x;
    for (int i = threadIdx.x; i < 4096; i += 256) {
        int dd = i >> 6, kk = i & 63;
        tl[dd][kk] = W[(size_t)(rr * HID + dd) * HID + kk];
    }
    __syncthreads();
    for (int i = threadIdx.x; i < 4096; i += 256) {
        int kk = i >> 6, dd = i & 63;
        WT[(size_t)rr * 4096 + kk * 64 + dd] = tl[dd][kk];
    }
}

// P[e*RS + rl*64 + d] = bf16(Wme0[(rr*64+d)*NUM_ENT + e]); grid (grels, net)
__global__ __launch_bounds__(256) void k_transpose(const float* __restrict__ W,
                                                   unsigned short* __restrict__ P,
                                                   int r0, int RS) {
    __shared__ float tile[64][65];
    int rl = blockIdx.x;
    int rr = r0 + rl;
    int e0 = blockIdx.y * 64;
    int tid = threadIdx.x;
    for (int i = tid; i < 4096; i += 256) {
        int dd = i >> 6, xx = i & 63;
        int e = e0 + xx;
        tile[dd][xx] = (e < NUM_ENT) ? W[(size_t)(rr * HID + dd) * NUM_ENT + e] : 0.f;
    }
    __syncthreads();
    for (int i = tid; i < 4096; i += 256) {
        int ee = i >> 6, dd = i & 63;
        int e = e0 + ee;
        if (e < NUM_ENT) P[(size_t)e * RS + (size_t)rl * 64 + dd] = f2bf(tile[dd][ee]);
    }
}

// B[e*RS + rl*64 + d] = bf16( sum_k A[e,k] * WT1[rr][k][d] )
// 1-D grid nwg = grels*net, bijective XCD-chunked swizzle, rr-minor decode.
__global__ __launch_bounds__(256) void k_gemmB(const float* __restrict__ A,
                                               const float* __restrict__ WT1,
                                               unsigned short* __restrict__ B,
                                               int r0, int RS, int grels) {
    __shared__ float Al[64][65];  // [e][k], pad 65: broadcast reads conflict-free
    __shared__ float Wl[64][68];  // [k][d], pad 68: aligned b128 reads, 2-way max
    int nwg = gridDim.x;
    int bid = blockIdx.x;
    int q = nwg >> 3, rm = nwg & 7;
    int xcd = bid & 7, sub = bid >> 3;
    int wg = (xcd < rm ? xcd * (q + 1) : rm * (q + 1) + (xcd - rm) * q) + sub;
    int etile = wg / grels;
    int rl = wg - etile * grels;
    int rr = r0 + rl;
    int e0 = etile * 64;
    int tid = threadIdx.x;

    for (int i = tid; i < 4096; i += 256) {
        int ee = i >> 6, kk = i & 63;
        int e = e0 + ee;
        Al[ee][kk] = (e < NUM_ENT) ? A[(size_t)e * HID + kk] : 0.f;
    }
    for (int i = tid; i < 4096; i += 256) {
        int kk = i >> 6, dd = i & 63;
        Wl[kk][dd] = WT1[(size_t)rr * 4096 + i];
    }
    __syncthreads();

    int di = tid & 15, ei = tid >> 4;
    float acc[4][4] = {};
#pragma unroll 4
    for (int k = 0; k < 64; ++k) {
        float4 w = *(const float4*)&Wl[k][di * 4];
        float a0 = Al[ei * 4 + 0][k];
        float a1 = Al[ei * 4 + 1][k];
        float a2 = Al[ei * 4 + 2][k];
        float a3 = Al[ei * 4 + 3][k];
        acc[0][0] = fmaf(a0, w.x, acc[0][0]); acc[0][1] = fmaf(a0, w.y, acc[0][1]);
        acc[0][2] = fmaf(a0, w.z, acc[0][2]); acc[0][3] = fmaf(a0, w.w, acc[0][3]);
        acc[1][0] = fmaf(a1, w.x, acc[1][0]); acc[1][1] = fmaf(a1, w.y, acc[1][1]);
        acc[1][2] = fmaf(a1, w.z, acc[1][2]); acc[1][3] = fmaf(a1, w.w, acc[1][3]);
        acc[2][0] = fmaf(a2, w.x, acc[2][0]); acc[2][1] = fmaf(a2, w.y, acc[2][1]);
        acc[2][2] = fmaf(a2, w.z, acc[2][2]); acc[2][3] = fmaf(a2, w.w, acc[2][3]);
        acc[3][0] = fmaf(a3, w.x, acc[3][0]); acc[3][1] = fmaf(a3, w.y, acc[3][1]);
        acc[3][2] = fmaf(a3, w.z, acc[3][2]); acc[3][3] = fmaf(a3, w.w, acc[3][3]);
    }
#pragma unroll
    for (int j = 0; j < 4; ++j) {
        int e = e0 + ei * 4 + j;
        if (e < NUM_ENT) {
            uint2 o;
            o.x = (unsigned)f2bf(acc[j][0]) | ((unsigned)f2bf(acc[j][1]) << 16);
            o.y = (unsigned)f2bf(acc[j][2]) | ((unsigned)f2bf(acc[j][3]) << 16);
            *(uint2*)&B[(size_t)e * RS + (size_t)rl * 64 + di * 4] = o;
        }
    }
}

// wave per tail: target[e,:] += sum_j (bf16 table[h_j, rl_j, :] + diag[rr_j,:])
__global__ __launch_bounds__(256) void k_scatter(const unsigned short* __restrict__ table,
                                                 const float* __restrict__ diag,
                                                 const int* __restrict__ toff,
                                                 const unsigned* __restrict__ bucket2,
                                                 float* __restrict__ target,
                                                 int RS, int g0, int applyAct) {
    int e = __builtin_amdgcn_readfirstlane(blockIdx.x * 4 + (threadIdx.x >> 6));
    int d = threadIdx.x & 63;
    if (e >= NUM_ENT) return;
    int j0 = toff[e], j1 = toff[e + 1];
    float acc = 0.f, acc2 = 0.f;
    int j = j0;
    for (; j + 2 <= j1; j += 2) {
        unsigned hr0 = bucket2[j], hr1 = bucket2[j + 1];
        int h0 = hr0 & 16383, ra = hr0 >> 14;
        int h1 = hr1 & 16383, rb = hr1 >> 14;
        float v0 = bf2f(table[(size_t)h0 * RS + (size_t)(ra - g0) * 64 + d]);
        float v1 = bf2f(table[(size_t)h1 * RS + (size_t)(rb - g0) * 64 + d]);
        acc  += v0 + diag[ra * 64 + d];
        acc2 += v1 + diag[rb * 64 + d];
    }
    if (j < j1) {
        unsigned hr0 = bucket2[j];
        int h0 = hr0 & 16383, ra = hr0 >> 14;
        acc += bf2f(table[(size_t)h0 * RS + (size_t)(ra - g0) * 64 + d]) + diag[ra * 64 + d];
    }
    acc += acc2;
    float v = target[e * HID + d] + acc;
    if (applyAct) v = (v >= 0.f) ? v : 0.01f * v;
    target[e * HID + d] = v;
}

// diag1[r,d] = sum_k Wpr0[k,r]*Wmr1[(r*64+d),k]; outrel[r,d] = sum_k Wpr0[k,r]*Wpr1[d,k]
__global__ void k_rel(const float* __restrict__ Wpr0, const float* __restrict__ Wmr1,
                      const float* __restrict__ Wpr1, float* __restrict__ diag1,
                      float* __restrict__ outrel) {
    __shared__ float wp[HID];
    int rr = blockIdx.x, d = threadIdx.x;
    wp[d] = Wpr0[d * NUM_REL + rr];
    __syncthreads();
    float s1 = 0.0f, s2 = 0.0f;
    const float* wmr = Wmr1 + (size_t)(rr * HID + d) * HID;
    const float* wpr = Wpr1 + d * HID;
    for (int k = 0; k < HID; k++) { s1 += wp[k] * wmr[k]; s2 += wp[k] * wpr[k]; }
    diag1[rr * HID + d] = s1;
    outrel[rr * HID + d] = s2;
}

// out[e,d] = sum_k A[e,k] * Wres1[d,k]
__global__ void k_init_u1(const float* __restrict__ A, const float* __restrict__ Wres1,
                          float* __restrict__ out) {
    __shared__ float W[HID][HID + 1];
    int tid = threadIdx.x;
    for (int i = tid; i < HID * HID; i += 256) W[i >> 6][i & 63] = Wres1[i];
    __syncthreads();
    int g = blockIdx.x * 256 + tid;
    int e = g >> 6, d = g & 63;
    if (e >= NUM_ENT) return;
    const float4* arow = (const float4*)(A + (size_t)e * HID);
    float acc = 0.0f;
#pragma unroll
    for (int k4 = 0; k4 < 16; k4++) {
        float4 a = arow[k4];
        acc = fmaf(a.x, W[d][k4 * 4 + 0], acc);
        acc = fmaf(a.y, W[d][k4 * 4 + 1], acc);
        acc = fmaf(a.z, W[d][k4 * 4 + 2], acc);
        acc = fmaf(a.w, W[d][k4 * 4 + 3], acc);
    }
    out[g] = acc;
}

// ============================================================
// fallback path (round-1 atomic kernels) — used only if ws too small
// ============================================================

__global__ void k_hist(const int* __restrict__ r, int* __restrict__ hist) {
    __shared__ int lh[NUM_REL];
    int tid = threadIdx.x;
    if (tid < NUM_REL) lh[tid] = 0;
    __syncthreads();
    int i = blockIdx.x * blockDim.x + tid;
    if (i < NTRIP) atomicAdd(&lh[r[i]], 1);
    __syncthreads();
    if (tid < NUM_REL && lh[tid] > 0) atomicAdd(&hist[tid], lh[tid]);
}

__global__ void k_scan_small(const int* __restrict__ hist, int* __restrict__ off,
                             int* __restrict__ cur) {
    if (threadIdx.x == 0 && blockIdx.x == 0) {
        int s = 0;
        for (int i = 0; i < NUM_REL; i++) { off[i] = s; cur[i] = s; s += hist[i]; }
        off[NUM_REL] = s;
    }
}

__global__ void k_bucket(const int* __restrict__ h, const int* __restrict__ r,
                         const int* __restrict__ t, int* __restrict__ cur,
                         int2* __restrict__ bucket) {
    __shared__ int lcnt[NUM_REL];
    __shared__ int lbase[NUM_REL];
    int tid = threadIdx.x;
    if (tid < NUM_REL) lcnt[tid] = 0;
    __syncthreads();
    int i = blockIdx.x * blockDim.x + tid;
    int rr = -1, lpos = 0;
    if (i < NTRIP) { rr = r[i]; lpos = atomicAdd(&lcnt[rr], 1); }
    __syncthreads();
    if (tid < NUM_REL && lcnt[tid] > 0) lbase[tid] = atomicAdd(&cur[tid], lcnt[tid]);
    __syncthreads();
    if (i < NTRIP) bucket[lbase[rr] + lpos] = make_int2(h[i], t[i]);
}

__global__ void k_l0(const float* __restrict__ Wme0, const float* __restrict__ Wmr0,
                     const int* __restrict__ off, const int2* __restrict__ bucket,
                     float* __restrict__ U0) {
    __shared__ float row[NUM_ENT];
    int rr = blockIdx.x >> 6;
    int d  = blockIdx.x & 63;
    const float4* src4 = (const float4*)(Wme0 + (size_t)(rr * HID + d) * NUM_ENT);
    float4* row4 = (float4*)row;
    for (int i = threadIdx.x; i < NUM_ENT / 4; i += blockDim.x) row4[i] = src4[i];
    __syncthreads();
    float wd0 = Wmr0[(size_t)(rr * HID + d) * NUM_REL + rr];
    int b0 = off[rr], b1 = off[rr + 1];
    for (int i = b0 + threadIdx.x; i < b1; i += blockDim.x) {
        int2 ht = bucket[i];
        atomicAdd(&U0[(size_t)ht.y * HID + d], row[ht.x] + wd0);
    }
}

__global__ void k_lrelu(float* __restrict__ x, int n) {
    int i = blockIdx.x * blockDim.x + threadIdx.x;
    if (i < n) { float v = x[i]; x[i] = v >= 0.0f ? v : 0.01f * v; }
}

#define L1_CHUNKS 16
__global__ void k_l1(const float* __restrict__ A, const float* __restrict__ Wme1,
                     const int* __restrict__ off, const int2* __restrict__ bucket,
                     const float* __restrict__ diag1, float* __restrict__ out) {
    int rr = blockIdx.x / L1_CHUNKS;
    int chunk = blockIdx.x % L1_CHUNKS;
    int b0 = off[rr], b1 = off[rr + 1];
    for (int i = b0 + chunk * 256 + (int)threadIdx.x; i < b1; i += L1_CHUNKS * 256) {
        int2 ht = bucket[i];
        const float4* arow = (const float4*)(A + (size_t)ht.x * HID);
        float4 a[16];
#pragma unroll
        for (int j = 0; j < 16; j++) a[j] = arow[j];
        float* op = out + (size_t)ht.y * HID;
#pragma unroll 4
        for (int d = 0; d < HID; d++) {
            const float4* m4 = (const float4*)(Wme1 + (size_t)(rr * HID + d) * HID);
            float acc = diag1[rr * HID + d];
#pragma unroll
            for (int k = 0; k < 16; k++) {
                float4 m = m4[k];
                acc = fmaf(a[k].x, m.x, acc);
                acc = fmaf(a[k].y, m.y, acc);
                acc = fmaf(a[k].z, m.z, acc);
                acc = fmaf(a[k].w, m.w, acc);
            }
            atomicAdd(op + d, acc);
        }
    }
}

// ============================================================
// launch
// ============================================================

static inline size_t align_up(size_t x, size_t a) { return (x + a - 1) & ~(a - 1); }

extern "C" void kernel_launch(void* const* d_in, const int* in_sizes, int n_in,
                              void* d_out, int out_size, void* d_ws, size_t ws_size,
                              hipStream_t stream) {
    const float* Wres0 = (const float*)d_in[0];
    const float* Wme0  = (const float*)d_in[1];
    const float* Wmr0  = (const float*)d_in[2];
    const float* Wpr0  = (const float*)d_in[3];
    const float* Wres1 = (const float*)d_in[4];
    const float* Wme1  = (const float*)d_in[5];
    const float* Wmr1  = (const float*)d_in[6];
    const float* Wpr1  = (const float*)d_in[7];
    const int* h = (const int*)d_in[8];
    const int* r = (const int*)d_in[9];
    const int* t = (const int*)d_in[10];
    float* out = (float*)d_out;  // [640000 ent | 3200 rel]

    char* ws = (char*)d_ws;
    const int nbt = (NTRIP + 255) / 256;       // 1954
    const int net = (NUM_ENT + 63) / 64;       // 157

    // pick largest relation-group size G that fits in ws (tables are bf16 now)
    int G = 0, ngroups = 0;
    size_t oP = 0, oB2 = 0, oToff = 0, oBins = 0, oU0 = 0, oD0 = 0, oD1 = 0, oWT = 0;
    for (int g = NUM_REL; g >= 1; --g) {
        int ng = (NUM_REL + g - 1) / g;
        size_t p = 0;
        size_t P_   = p; p += align_up((size_t)g * 64 * NUM_ENT * 2, 256);   // bf16
        size_t B2_  = p; p += align_up((size_t)NTRIP * 4, 256);
        size_t Tf_  = p; p += align_up(((size_t)ng * NUM_ENT + 1) * 4, 256);
        size_t Bn_  = p; p += align_up((size_t)ng * NUM_ENT * 4, 256);
        size_t U0_  = p; p += align_up((size_t)NUM_ENT * HID * 4, 256);
        size_t D0_  = p; p += align_up((size_t)NUM_REL * HID * 4, 256);
        size_t D1_  = p; p += align_up((size_t)NUM_REL * HID * 4, 256);
        size_t WT_  = p; p += align_up((size_t)NUM_REL * HID * HID * 4, 256);
        if (p <= ws_size) {
            G = g; ngroups = ng;
            oP = P_; oB2 = B2_; oToff = Tf_; oBins = Bn_; oU0 = U0_; oD0 = D0_;
            oD1 = D1_; oWT = WT_;
            break;
        }
    }

    if (G >= 1) {
        unsigned short* P     = (unsigned short*)(ws + oP);
        unsigned* bucket2     = (unsigned*)(ws + oB2);
        int*      toff        = (int*)(ws + oToff);
        int*      bins        = (int*)(ws + oBins);
        float*    U0          = (float*)(ws + oU0);
        float*    diag0       = (float*)(ws + oD0);
        float*    diag1       = (float*)(ws + oD1);
        float*    WT1         = (float*)(ws + oWT);
        int nbins = ngroups * NUM_ENT;
        int RS = G * 64;

        hipMemsetAsync(bins, 0, (size_t)nbins * 4, stream);
        k_thist<<<nbt, 256, 0, stream>>>(r, t, bins, G);
        k_scan<<<1, 1024, 0, stream>>>(bins, toff, nbins);
        k_tscatter<<<nbt, 256, 0, stream>>>(h, r, t, bins, bucket2, G);

        k_diag0<<<(NUM_REL * HID + 255) / 256, 256, 0, stream>>>(Wmr0, diag0);
        k_init_u0<<<net, 256, 0, stream>>>(Wres0, U0);
        k_transposeW1<<<NUM_REL, 256, 0, stream>>>(Wme1, WT1);

        // layer 0: per group, transpose Wme0 chunk (bf16) then tail-owned scatter
        for (int g = 0; g < ngroups; ++g) {
            int grels = (g == ngroups - 1) ? (NUM_REL - g * G) : G;
            k_transpose<<<dim3(grels, net), 256, 0, stream>>>(Wme0, P, g * G, RS);
            k_scatter<<<(NUM_ENT + 3) / 4, 256, 0, stream>>>(
                P, diag0, toff + (size_t)g * NUM_ENT, bucket2, U0, RS, g * G,
                (g == ngroups - 1) ? 1 : 0);
        }
        // U0 is now A (activated)

        k_rel<<<NUM_REL, HID, 0, stream>>>(Wpr0, Wmr1, Wpr1, diag1, out + NUM_ENT * HID);
        k_init_u1<<<(NUM_ENT * HID) / 256, 256, 0, stream>>>(U0, Wres1, out);

        // layer 1: per group, dense bf16 B = A @ Wme1_r^T then tail-owned scatter
        for (int g = 0; g < ngroups; ++g) {
            int grels = (g == ngroups - 1) ? (NUM_REL - g * G) : G;
            k_gemmB<<<grels * net, 256, 0, stream>>>(U0, WT1, P, g * G, RS, grels);
            k_scatter<<<(NUM_ENT + 3) / 4, 256, 0, stream>>>(
                P, diag1, toff + (size_t)g * NUM_ENT, bucket2, out, RS, g * G,
                (g == ngroups - 1) ? 1 : 0);
        }
        return;
    }

    // ---------- fallback: round-1 atomic path (ws >= 6.6 MB known-good) ----------
    {
        int2*  bucket = (int2*)ws;                    // 4,000,000 B
        float* U0     = (float*)(ws + 4000000);       // 2,560,000 B
        float* diag1  = (float*)(ws + 6560000);       // 12,800 B
        int*   hist   = (int*)(ws + 6572800);
        int*   off    = (int*)(ws + 6573056);
        int*   cur    = (int*)(ws + 6573312);

        hipMemsetAsync(hist, 0, NUM_REL * sizeof(int), stream);
        k_hist<<<nbt, 256, 0, stream>>>(r, hist);
        k_scan_small<<<1, 64, 0, stream>>>(hist, off, cur);
        k_bucket<<<nbt, 256, 0, stream>>>(h, r, t, cur, bucket);

        k_init_u0<<<net, 256, 0, stream>>>(Wres0, U0);
        k_l0<<<NUM_REL * HID, 256, 0, stream>>>(Wme0, Wmr0, off, bucket, U0);
        k_lrelu<<<(NUM_ENT * HID + 255) / 256, 256, 0, stream>>>(U0, NUM_ENT * HID);

        k_rel<<<NUM_REL, HID, 0, stream>>>(Wpr0, Wmr1, Wpr1, diag1, out + NUM_ENT * HID);
        k_init_u1<<<(NUM_ENT * HID) / 256, 256, 0, stream>>>(U0, Wres1, out);
        k_l1<<<NUM_REL * L1_CHUNKS, 256, 0, stream>>>(U0, Wme1, off, bucket, diag1, out);
        k_lrelu<<<(NUM_ENT * HID + 255) / 256, 256, 0, stream>>>(out, NUM_ENT * HID);
    }
}